// Round 7
// baseline (283.151 us; speedup 1.0000x reference)
//
#include <hip/hip_runtime.h>
#include <hip/hip_fp16.h>

// patches_generator: bilinear grid_sample (border, align_corners=False)
// fm:   [N=16, C=128, H=112, W=112] f32
// grid: [N, P=98, 16, 16, 2] f32  (x,y) in [-1,1]
// out:  [N, P, C, 16, 16] f32
//
// Round-7: tail elimination + wide stores, on top of r6's fp16 channel-pair
// LDS packing (which was confirmed +12us).
// r6 accounting: VALU ~13us + LDS ~12us + HBM ~48us != 98us measured; the
// ~25us residual matches the block-tail: 1024 blocks at 3-resident/CU = 4
// sequential slots, last slot only 1 block/CU (8 waves, nothing to overlap).
// Fix 1: 512 blocks = exactly 2/CU, each handling TWO channel-pairs
//        sequentially with LDS re-staging (co-resident block overlaps it).
// Fix 2: each thread-iter = 4 consecutive sample points x 2 channels:
//        grid read 32 B/lane (2x dwordx4), output 2x nt dwordx4 stores
//        (1 KB/wave/instr; store instrs / 4).

#define NN 16
#define CC 128
#define HH 112
#define WW 112
#define PP 98
#define PTS 256                  // 16x16 sample points per patch
#define NPTS (PP * PTS)          // 25088 points per batch image
#define NQUADS (NPTS / 4)        // 6272 point-quads
#define HWs (HH * WW)            // 12544 pixels; 4 B each (2x fp16) = 49 KB
#define PAD 113                  // pad row: border taps in-bounds, weight 0
#define THREADS 512

typedef float f32x4 __attribute__((ext_vector_type(4)));
typedef unsigned int u32x4 __attribute__((ext_vector_type(4)));

__device__ __forceinline__ unsigned int pack2(float a, float b) {
  __half2 h = __floats2half2_rn(a, b);   // v_cvt_pkrtz_f16_f32
  return *reinterpret_cast<unsigned int*>(&h);
}

// one bilinear sample from the fp16-packed pair plane -> (chanA, chanB)
__device__ __forceinline__ float2 samp(const unsigned int* __restrict__ plane,
                                       float gx, float gy) {
  const float x = fminf(fmaxf(fmaf(gx, (float)WW * 0.5f, (float)WW * 0.5f - 0.5f),
                              0.0f), (float)(WW - 1));
  const float y = fminf(fmaxf(fmaf(gy, (float)HH * 0.5f, (float)HH * 0.5f - 0.5f),
                              0.0f), (float)(HH - 1));
  const float x0f = floorf(x), y0f = floorf(y);
  const float wx = x - x0f, wy = y - y0f;
  // two ds_read2_b32; x1/y1 clamps unneeded (weight exactly 0 at border,
  // pad row keeps the reads in-bounds and finite)
  const unsigned int* p0 = reinterpret_cast<const unsigned int*>(
      reinterpret_cast<const char*>(plane) + ((int)y0f * WW + (int)x0f) * 4);
  const __half2 h00 = *reinterpret_cast<const __half2*>(&p0[0]);
  const __half2 h01 = *reinterpret_cast<const __half2*>(&p0[1]);
  const __half2 h10 = *reinterpret_cast<const __half2*>(&p0[WW]);
  const __half2 h11 = *reinterpret_cast<const __half2*>(&p0[WW + 1]);
  const float2 f00 = __half22float2(h00);
  const float2 f01 = __half22float2(h01);
  const float2 f10 = __half22float2(h10);
  const float2 f11 = __half22float2(h11);
  const float ux = 1.0f - wx, uy = 1.0f - wy;
  const float w00 = uy * ux, w01 = uy * wx, w10 = wy * ux, w11 = wy * wx;
  float2 r;
  r.x = fmaf(f11.x, w11, fmaf(f10.x, w10, fmaf(f01.x, w01, f00.x * w00)));
  r.y = fmaf(f11.y, w11, fmaf(f10.y, w10, fmaf(f01.y, w01, f00.y * w00)));
  return r;
}

__global__ __launch_bounds__(THREADS) void patches_kernel(
    const float* __restrict__ fm,
    const float* __restrict__ grid,
    float* __restrict__ out) {
  __shared__ unsigned int plane[HWs + PAD];

  const int n = blockIdx.y;
  const int t = threadIdx.x;
  const f32x4* __restrict__ g4 =
      reinterpret_cast<const f32x4*>(grid + (size_t)n * NPTS * 2);

  // two channel-pairs per block, sequentially (512 blocks = exactly 2/CU)
  for (int half = 0; half < 2; ++half) {
    const int cp = blockIdx.x * 2 + half;   // channel pair index
    const int c0 = cp * 2;                  // channels c0, c0+1

    if (half) __syncthreads();              // all compute on prev plane done

    // ---- stage both planes, nontemporal f32x4 loads, pack to fp16x2 ----
    const f32x4* __restrict__ srcA =
        reinterpret_cast<const f32x4*>(fm + ((size_t)n * CC + c0) * HWs);
    const f32x4* __restrict__ srcB =
        reinterpret_cast<const f32x4*>(fm + ((size_t)n * CC + c0 + 1) * HWs);
    u32x4* dst = reinterpret_cast<u32x4*>(plane);
    for (int i = t; i < HWs / 4; i += THREADS) {
      const f32x4 a = __builtin_nontemporal_load(&srcA[i]);
      const f32x4 b = __builtin_nontemporal_load(&srcB[i]);
      u32x4 q;
      q.x = pack2(a.x, b.x);
      q.y = pack2(a.y, b.y);
      q.z = pack2(a.z, b.z);
      q.w = pack2(a.w, b.w);
      dst[i] = q;                            // ds_write_b128, coalesced
    }
    if (t < PAD) plane[HWs + t] = 0u;        // zero pad row
    __syncthreads();

    // out base for (n, p=0, c0, s=0); channel c0+1 is +PTS floats
    float* __restrict__ obase = out + ((size_t)n * PP * CC + c0) * PTS;

    // 6272 quads / 512 threads = 12 full iters + 128-thread tail
#pragma unroll 2
    for (int it = 0; it < 13; ++it) {
      const int q = t + it * THREADS;
      if (q < NQUADS) {
        const f32x4 ga = g4[q * 2];          // points 4q, 4q+1
        const f32x4 gb = g4[q * 2 + 1];      // points 4q+2, 4q+3
        const float2 r0 = samp(plane, ga.x, ga.y);
        const float2 r1 = samp(plane, ga.z, ga.w);
        const float2 r2 = samp(plane, gb.x, gb.y);
        const float2 r3 = samp(plane, gb.z, gb.w);
        f32x4 vA, vB;
        vA.x = r0.x; vA.y = r1.x; vA.z = r2.x; vA.w = r3.x;
        vB.x = r0.y; vB.y = r1.y; vB.z = r2.y; vB.w = r3.y;
        const int p = q >> 6;                // patch
        const int s4 = (q & 63) * 4;         // first sample of the quad
        float* o = obase + (size_t)p * CC * PTS + s4;
        __builtin_nontemporal_store(vA, reinterpret_cast<f32x4*>(o));
        __builtin_nontemporal_store(vB, reinterpret_cast<f32x4*>(o + PTS));
      }
    }
  }
}

extern "C" void kernel_launch(void* const* d_in, const int* in_sizes, int n_in,
                              void* d_out, int out_size, void* d_ws, size_t ws_size,
                              hipStream_t stream) {
  const float* fm = (const float*)d_in[0];
  const float* grid = (const float*)d_in[1];
  float* out = (float*)d_out;

  dim3 grd(CC / 4, NN);   // 512 blocks: (n, two channel-pairs) each = 2/CU exact
  dim3 blk(THREADS);
  patches_kernel<<<grd, blk, 0, stream>>>(fm, grid, out);
}